// Round 4
// baseline (417.278 us; speedup 1.0000x reference)
//
#include <hip/hip_runtime.h>
#include <hip/hip_bf16.h>

// Complex ConvLSTM cell. Inputs f32, output f32 (verified, absmax 0.0625).
//   Zp: halo-padded packed activations, [b][y' 0..65][x' 0..65][cin 0..255] bf16
//       cin = [x lo | h lo | x hi | h hi]; halo = zeros.
//   Wp[n][tap][cin]: n = part*64+ch, parts {yr_i,yi_i,yr_o,yi_o,yr_c,yi_c};
//       yr -> [Wr ; -Wi], yi -> [Wi ; Wr].
//   conv_gemm R4: A (weights) read DIRECTLY from global/L2 as MFMA frags --
//       no A LDS staging (R1-R3 were LDS-BW-bound: 18.8 MB/CU; now ~8 MB).
//       LDS holds only B (double-buffered, 33 KB). One barrier per B-tile
//       (12 total); inner 2 steps barrier-free. Register-pipelined frags
//       (af0/bf0 current, af1/bf1 next phase). Accumulation order identical
//       to R1-R3.
//   prep_kernel: fused halo_zero + pack_z + pack_w (5 -> 3 launches).
//   epilogue: gate math -> h_new, c_new (f32), 8 px/thread vectorized.

typedef __attribute__((ext_vector_type(8))) short short8;
typedef __attribute__((ext_vector_type(4))) float floatx4;
typedef __attribute__((ext_vector_type(4))) float float4v;

#define MTOT   65536
#define HSIZE  8388608

__device__ __forceinline__ short f2bf(float f) {
  __hip_bfloat16 h = __float2bfloat16(f);
  return *reinterpret_cast<short*>(&h);
}

__device__ __forceinline__ float bf2f(short s) {
  unsigned u = ((unsigned)(unsigned short)s) << 16;
  return __uint_as_float(u);
}

__device__ __forceinline__ void gload16(const short* g, void* lds) {
  __builtin_amdgcn_global_load_lds(
      (__attribute__((address_space(1))) void*)(g),
      (__attribute__((address_space(3))) void*)(lds), 16, 0, 0);
}

// ---------------------------------------------------------------- fused prep
// blocks [0,520): halo zero; [520,4616): pack_z; [4616,8072): pack_w+bias.
__global__ __launch_bounds__(256) void prep_kernel(
    const float* __restrict__ xs, const float* __restrict__ hs,
    short* __restrict__ Zp,
    const float* __restrict__ Wr_i, const float* __restrict__ Wi_i,
    const float* __restrict__ Wr_o, const float* __restrict__ Wi_o,
    const float* __restrict__ Wr_c, const float* __restrict__ Wi_c,
    const float* __restrict__ br_i, const float* __restrict__ bi_i,
    const float* __restrict__ br_o, const float* __restrict__ bi_o,
    const float* __restrict__ br_c, const float* __restrict__ bi_c,
    short* __restrict__ Wp, float* __restrict__ bias) {
  __shared__ short tile[64 * 72];
  int blk = blockIdx.x;
  int tid = threadIdx.x;

  if (blk < 520) {                        // ---- halo zero
    int t = blk * 256 + tid;              // 4160 px * 32
    int s   = t & 31;
    int pix = t >> 5;
    int b = pix / 260;
    int r = pix - b * 260;
    int yp, xp;
    if (r < 66)       { yp = 0;               xp = r; }
    else if (r < 132) { yp = 65;              xp = r - 66; }
    else { int r2 = r - 132; yp = 1 + (r2 >> 1); xp = (r2 & 1) * 65; }
    short8 z;
#pragma unroll
    for (int q = 0; q < 8; ++q) z[q] = 0;
    *(short8*)(Zp + (((b * 66 + yp) * 66 + xp) * 256 + s * 8)) = z;
    return;
  }

  if (blk < 520 + 4096) {                 // ---- pack Z (tiled transpose)
    int bid = blk - 520;
    int y      = bid & 63;
    int half   = (bid >> 6) & 1;
    int srcSel = (bid >> 7) & 1;
    int b      = bid >> 8;
    const float* src = srcSel ? hs : xs;
    int chBase  = half * 64;
    int cinBase = half * 128 + srcSel * 64;
    int x4 = tid & 15, chq = tid >> 4;
#pragma unroll
    for (int p = 0; p < 4; ++p) {
      int ch = p * 16 + chq;
      float4v f = *(const float4v*)(src + (size_t)(b * 128 + chBase + ch) * 4096 + y * 64 + x4 * 4);
#pragma unroll
      for (int e = 0; e < 4; ++e)
        tile[(x4 * 4 + e) * 72 + ch] = f2bf(f[e]);
    }
    __syncthreads();
    int x = tid >> 2, seg = tid & 3;
    short8 v0 = *(const short8*)(tile + x * 72 + seg * 16);
    short8 v1 = *(const short8*)(tile + x * 72 + seg * 16 + 8);
    size_t outp = ((size_t)(b * 66 + y + 1) * 66 + x + 1) * 256 + cinBase + seg * 16;
    *(short8*)(Zp + outp)     = v0;
    *(short8*)(Zp + outp + 8) = v1;
    return;
  }

  {                                       // ---- pack W + bias
    int g = (blk - 4616) * 256 + tid;
    if (g >= 384 * 9 * 256) return;
    int cin = g & 255;
    int tap = (g >> 8) % 9;
    int n   = g / (256 * 9);
    int part = n >> 6, ch = n & 63;
    const float *Wr, *Wi;
    if (part < 2)      { Wr = Wr_i; Wi = Wi_i; }
    else if (part < 4) { Wr = Wr_o; Wi = Wi_o; }
    else               { Wr = Wr_c; Wi = Wi_c; }
    int im = part & 1;
    int ci = cin & 127;
    int second = cin >> 7;
    const float* src = im ? (second ? Wr : Wi) : (second ? Wi : Wr);
    float f = src[(ch * 128 + ci) * 9 + tap];
    if (!im && second) f = -f;
    Wp[(n * 9 + tap) * 256 + cin] = f2bf(f);
    if (g < 384) {
      int p2 = g >> 6, c2 = g & 63;
      const float* bs = (p2 == 0) ? br_i : (p2 == 1) ? bi_i : (p2 == 2) ? br_o
                      : (p2 == 3) ? bi_o : (p2 == 4) ? br_c : bi_c;
      bias[g] = bs[c2];
    }
  }
}

// ---------------------------------------------------------------- implicit GEMM (A from L2)
// 128ch x 128px tile, 4 waves (each 64x64), K = 9 taps x 256 cin.
// B-tiles t = dyi*4 + c0i (12 of them), each covers 3 dx steps.
// LDS: Bs[2][2 r2][66 cols][8 slots], XOR k-group swizzle; A never staged.
__device__ __forceinline__ void issueB(const short* __restrict__ Z, int zrow0,
                                       int tb, short8* dst, int tid, int wv) {
  int dy = tb >> 2;
  int c0 = (tb & 3) * 64;
#pragma unroll
  for (int it = 0; it < 4; ++it) {
    int idx = tid + it * 256;           // 0..1023: r2 = idx>>9, col = (idx&511)>>3 + 1
    int r2  = idx >> 9;
    int rem = idx & 511;
    int col = (rem >> 3) + 1;           // cols 1..64 (0 and 65 are permanent zeros)
    int p   = rem & 7;
    int g   = p ^ (col & 7);
    int ygl = zrow0 + dy + r2;
    int idx0 = it * 256 + wv * 64;      // wave-uniform dest base
    int r2d  = idx0 >> 9;
    int rem0 = idx0 & 511;
    gload16(Z + ((size_t)(ygl * 66 + col) * 256 + c0 + g * 8),
            (void*)(dst + (r2d * 528 + 8 + rem0)));
  }
}

// A-frag direct load: a[i] = Wp[(n0+wch+i*16+l15)*2304 + tap*256 + c0 + (KK*4+l4)*8]
template<int KK>
__device__ __forceinline__ void loadA(const short* __restrict__ Wp,
                                      const int (&aoff)[4], int tapc0,
                                      short8 (&a)[4]) {
#pragma unroll
  for (int i = 0; i < 4; ++i)
    a[i] = *(const short8*)(Wp + aoff[i] + tapc0 + KK * 32);
}

template<int KK, int DXI>
__device__ __forceinline__ void fragB(const short8* __restrict__ Bb,
                                      short8 (&bv)[4], int r2w, int l15, int l4) {
  int kg = KK * 4 + l4;
#pragma unroll
  for (int j = 0; j < 4; ++j) {
    int col = j * 16 + l15 + DXI;
    bv[j] = Bb[r2w * 528 + col * 8 + (kg ^ (col & 7))];
  }
}

__device__ __forceinline__ void mfma16(const short8 (&a)[4], const short8 (&bv)[4],
                                       floatx4 (&acc)[4][4]) {
  __builtin_amdgcn_s_setprio(1);
#pragma unroll
  for (int i = 0; i < 4; ++i)
#pragma unroll
    for (int j = 0; j < 4; ++j)
      acc[i][j] = __builtin_amdgcn_mfma_f32_16x16x32_bf16(a[i], bv[j], acc[i][j], 0, 0, 0);
  __builtin_amdgcn_s_setprio(0);
}

__global__ __launch_bounds__(256, 2) void conv_gemm(
    const short* __restrict__ Z, const short* __restrict__ Wp,
    const float* __restrict__ bias, __hip_bfloat16* __restrict__ gates) {
  __shared__ short8 Bs[2][1056];   // 33 KiB total

  const int tid = threadIdx.x;
  const int wv = tid >> 6, lane = tid & 63;
  const int l15 = lane & 15, l4 = lane >> 4;
  const int m0 = blockIdx.x * 128;
  const int n0 = blockIdx.y * 128;
  const int b  = m0 >> 12;
  const int y0 = (m0 >> 6) & 63;    // even
  const int zrow0 = b * 66 + y0;
  const int wch = (wv & 1) * 64;
  const int r2w = wv >> 1;

  int aoff[4];
#pragma unroll
  for (int i = 0; i < 4; ++i)
    aoff[i] = (n0 + wch + i * 16 + l15) * 2304 + l4 * 8;

  floatx4 acc[4][4];
#pragma unroll
  for (int i = 0; i < 4; ++i)
#pragma unroll
    for (int j = 0; j < 4; ++j)
#pragma unroll
      for (int r = 0; r < 4; ++r) acc[i][j][r] = 0.f;

  short8 af0[4], bf0[4], af1[4], bf1[4];

  // -- prologue: zero permanent halo cols of both B bufs; stage B[0];
  //    publish; preload frags (t=0, dx=0, kk=0).
  if (tid < 64) {
    int buf = tid >> 5, w = tid & 31;
    int r2 = w >> 4, hi = (w >> 3) & 1, p = w & 7;
    short8 z;
#pragma unroll
    for (int q = 0; q < 8; ++q) z[q] = 0;
    Bs[buf][r2 * 528 + (hi ? 520 : 0) + p] = z;
  }
  issueB(Z, zrow0, 0, &Bs[0][0], tid, wv);
  __builtin_amdgcn_sched_barrier(0);
  asm volatile("s_waitcnt vmcnt(0) lgkmcnt(0)" ::: "memory");
  __builtin_amdgcn_sched_barrier(0);
  __builtin_amdgcn_s_barrier();
  __builtin_amdgcn_sched_barrier(0);
  loadA<0>(Wp, aoff, 0, af0);
  fragB<0, 0>(&Bs[0][0], bf0, r2w, l15, l4);

  for (int t = 0; t < 12; ++t) {
    const short8* Bcur = &Bs[t & 1][0];
    short8*       Bnxt = &Bs[(t & 1) ^ 1][0];
    const int tc = ((t >> 2) * 3) * 256 + (t & 3) * 64;   // tap(dx=-1)*256 + c0

    if (t < 11) issueB(Z, zrow0, t + 1, Bnxt, tid, wv);

    // dx = -1 (DXI 0), taps tc
    loadA<1>(Wp, aoff, tc, af1);        fragB<1, 0>(Bcur, bf1, r2w, l15, l4);
    mfma16(af0, bf0, acc);
    loadA<0>(Wp, aoff, tc + 256, af0);  fragB<0, 1>(Bcur, bf0, r2w, l15, l4);
    mfma16(af1, bf1, acc);
    // dx = 0 (DXI 1), taps tc+256
    loadA<1>(Wp, aoff, tc + 256, af1);  fragB<1, 1>(Bcur, bf1, r2w, l15, l4);
    mfma16(af0, bf0, acc);
    loadA<0>(Wp, aoff, tc + 512, af0);  fragB<0, 2>(Bcur, bf0, r2w, l15, l4);
    mfma16(af1, bf1, acc);
    // dx = +1 (DXI 2), taps tc+512
    loadA<1>(Wp, aoff, tc + 512, af1);  fragB<1, 2>(Bcur, bf1, r2w, l15, l4);
    mfma16(af0, bf0, acc);
    mfma16(af1, bf1, acc);

    // ---- B-tile transition: my B[t+1] gloads drained, then barrier.
    __builtin_amdgcn_sched_barrier(0);
    asm volatile("s_waitcnt vmcnt(0)" ::: "memory");
    __builtin_amdgcn_sched_barrier(0);
    __builtin_amdgcn_s_barrier();
    __builtin_amdgcn_sched_barrier(0);
    if (t < 11) {
      const int tn = t + 1;
      const int tcn = ((tn >> 2) * 3) * 256 + (tn & 3) * 64;
      loadA<0>(Wp, aoff, tcn, af0);
      fragB<0, 0>(Bnxt, bf0, r2w, l15, l4);
    }
  }

#pragma unroll
  for (int i = 0; i < 4; ++i)
#pragma unroll
    for (int j = 0; j < 4; ++j)
#pragma unroll
      for (int r = 0; r < 4; ++r) {
        int ch = n0 + wch + i * 16 + l4 * 4 + r;
        int px = m0 + r2w * 64 + j * 16 + l15;
        gates[(size_t)ch * MTOT + px] = __float2bfloat16(acc[i][j][r] + bias[ch]);
      }
}

// ---------------------------------------------------------------- epilogue (f32 out)
// 8 px/thread, all accesses 8-16B/lane. 2048 blocks x 256 threads.
__device__ __forceinline__ float fsig(float v) { return 1.f / (1.f + __expf(-v)); }
__device__ __forceinline__ float ftanh(float v) {
  float e = __expf(2.f * v);
  return 1.f - 2.f / (e + 1.f);
}

__global__ __launch_bounds__(256) void epilogue_kernel(
    const __hip_bfloat16* __restrict__ gates,
    const float* __restrict__ x,
    const float* __restrict__ c_prev,
    float* __restrict__ out) {
  int t = blockIdx.x * 256 + threadIdx.x;     // 524,288 threads total
  int ch = t >> 13;                           // 0..63
  int m  = (t & 8191) << 3;                   // 8 consecutive pixels
  int b = m >> 12, sp = m & 4095;

  size_t gbase = (size_t)ch * MTOT + m;
  short8 gri = *(const short8*)((const short*)gates + gbase);
  short8 gii = *(const short8*)((const short*)gates + gbase + (size_t)64 * MTOT);
  short8 gro = *(const short8*)((const short*)gates + gbase + (size_t)128 * MTOT);
  short8 gio = *(const short8*)((const short*)gates + gbase + (size_t)192 * MTOT);
  short8 grc = *(const short8*)((const short*)gates + gbase + (size_t)256 * MTOT);
  short8 gic = *(const short8*)((const short*)gates + gbase + (size_t)320 * MTOT);

  int base = (b * 128 + ch) * 4096 + sp;
  float xr[8] __attribute__((aligned(16)));
  float xi[8] __attribute__((aligned(16)));
  float cr[8] __attribute__((aligned(16)));
  float ci[8] __attribute__((aligned(16)));
  *(float4v*)(xr)     = *(const float4v*)(x + base);
  *(float4v*)(xr + 4) = *(const float4v*)(x + base + 4);
  *(float4v*)(xi)     = *(const float4v*)(x + base + 64 * 4096);
  *(float4v*)(xi + 4) = *(const float4v*)(x + base + 64 * 4096 + 4);
  *(float4v*)(cr)     = *(const float4v*)(c_prev + base);
  *(float4v*)(cr + 4) = *(const float4v*)(c_prev + base + 4);
  *(float4v*)(ci)     = *(const float4v*)(c_prev + base + 64 * 4096);
  *(float4v*)(ci + 4) = *(const float4v*)(c_prev + base + 64 * 4096 + 4);

  float hr[8] __attribute__((aligned(16)));
  float hi[8] __attribute__((aligned(16)));
  float nr[8] __attribute__((aligned(16)));
  float ni[8] __attribute__((aligned(16)));
#pragma unroll
  for (int q = 0; q < 8; ++q) {
    float i_r = fsig(bf2f(gri[q])), i_i = fsig(bf2f(gii[q]));
    float o_r = fsig(bf2f(gro[q])), o_i = fsig(bf2f(gio[q]));
    float ct_r = ftanh(bf2f(grc[q])), ct_i = ftanh(bf2f(gic[q]));
    float cnr = xr[q] * cr[q] - xi[q] * ci[q] + i_r * ct_r - i_i * ct_i;
    float cni = xr[q] * ci[q] + xi[q] * cr[q] + i_r * ct_i + i_i * ct_r;
    float tr = ftanh(cnr), ti = ftanh(cni);
    hr[q] = o_r * tr - o_i * ti;
    hi[q] = o_r * ti + o_i * tr;
    nr[q] = cnr;
    ni[q] = cni;
  }

  *(float4v*)(out + base)                         = *(const float4v*)(hr);
  *(float4v*)(out + base + 4)                     = *(const float4v*)(hr + 4);
  *(float4v*)(out + base + 64 * 4096)             = *(const float4v*)(hi);
  *(float4v*)(out + base + 64 * 4096 + 4)         = *(const float4v*)(hi + 4);
  *(float4v*)(out + HSIZE + base)                 = *(const float4v*)(nr);
  *(float4v*)(out + HSIZE + base + 4)             = *(const float4v*)(nr + 4);
  *(float4v*)(out + HSIZE + base + 64 * 4096)     = *(const float4v*)(ni);
  *(float4v*)(out + HSIZE + base + 64 * 4096 + 4) = *(const float4v*)(ni + 4);
}

// ---------------------------------------------------------------- launch
extern "C" void kernel_launch(void* const* d_in, const int* in_sizes, int n_in,
                              void* d_out, int out_size, void* d_ws, size_t ws_size,
                              hipStream_t stream) {
  // inputs: 0 x, 1 h_prev, 2 c_prev,
  //         3 Wr_i, 4 Wi_i, 5 br_i, 6 bi_i,  7..10 f-gate (unused),
  //        11 Wr_o,12 Wi_o,13 br_o,14 bi_o, 15 Wr_c,16 Wi_c,17 br_c,18 bi_c
  char* ws = (char*)d_ws;
  short* Zp   = (short*)ws;                          // 35,684,352 B
  short* Wp   = (short*)(ws + 35684352);             //  1,769,472 B
  float* bias = (float*)(ws + 37453824);             //      1,536 B
  __hip_bfloat16* gates = (__hip_bfloat16*)(ws + 37455360); // 50,331,648 B
  // total ~87.8 MiB

  prep_kernel<<<8072, 256, 0, stream>>>(
      (const float*)d_in[0], (const float*)d_in[1], Zp,
      (const float*)d_in[3], (const float*)d_in[4],
      (const float*)d_in[11], (const float*)d_in[12],
      (const float*)d_in[15], (const float*)d_in[16],
      (const float*)d_in[5], (const float*)d_in[6],
      (const float*)d_in[13], (const float*)d_in[14],
      (const float*)d_in[17], (const float*)d_in[18],
      Wp, bias);
  conv_gemm<<<dim3(512, 3), 256, 0, stream>>>(Zp, Wp, bias, gates);
  epilogue_kernel<<<2048, 256, 0, stream>>>(
      gates, (const float*)d_in[0], (const float*)d_in[2],
      (float*)d_out);
}

// Round 5
// 309.954 us; speedup vs baseline: 1.3463x; 1.3463x over previous
//
#include <hip/hip_runtime.h>
#include <hip/hip_bf16.h>

// Complex ConvLSTM cell. Inputs f32, output f32.
//   Zp: halo-padded packed activations, [b][y' 0..65][x' 0..65][cin 0..255] bf16
//   Wp[n][tap][cin]: n = part*64+ch, parts {yr_i,yi_i,yr_o,yi_o,yr_c,yi_c}
//   conv_fused R5: block = 384ch x 128px (2 y-rows), 8 waves, wave tile 96x64.
//     K-step 32 (one MFMA-K), 72 steps = 8 cin-chunks (kc) x 9 taps.
//     B (4 input rows x 66 cols x 32k) staged once per kc, serves all 9 taps
//     via row(dy)/col(dx) offsets. A (384x32k) staged per step, double-buffered.
//     R3 pipeline skeleton: frags(s+1) read post-barrier, pure-reg MFMA,
//     counted vmcnt (1 at taps 1,2 else 0), uniform issue counts (kc=8
//     prefetches are in-bounds junk into dead buffers, drained before reuse).
//     Epilogue FUSED: acc -> LDS exchange (49KB, reuses As), 2 px-row rounds,
//     gate math -> h_new, c_new written directly (gates never hit HBM).
//   prep_kernel: fused halo_zero + pack_z + pack_w (unchanged, verified R4).

typedef __attribute__((ext_vector_type(8))) short short8;
typedef __attribute__((ext_vector_type(4))) float floatx4;
typedef __attribute__((ext_vector_type(4))) float float4v;

#define HSIZE  8388608

__device__ __forceinline__ short f2bf(float f) {
  __hip_bfloat16 h = __float2bfloat16(f);
  return *reinterpret_cast<short*>(&h);
}

__device__ __forceinline__ float bf2f(short s) {
  unsigned u = ((unsigned)(unsigned short)s) << 16;
  return __uint_as_float(u);
}

__device__ __forceinline__ void gload16(const short* g, void* lds) {
  __builtin_amdgcn_global_load_lds(
      (__attribute__((address_space(1))) void*)(g),
      (__attribute__((address_space(3))) void*)(lds), 16, 0, 0);
}

// ---------------------------------------------------------------- fused prep
// blocks [0,520): halo zero; [520,4616): pack_z; [4616,8072): pack_w+bias.
__global__ __launch_bounds__(256) void prep_kernel(
    const float* __restrict__ xs, const float* __restrict__ hs,
    short* __restrict__ Zp,
    const float* __restrict__ Wr_i, const float* __restrict__ Wi_i,
    const float* __restrict__ Wr_o, const float* __restrict__ Wi_o,
    const float* __restrict__ Wr_c, const float* __restrict__ Wi_c,
    const float* __restrict__ br_i, const float* __restrict__ bi_i,
    const float* __restrict__ br_o, const float* __restrict__ bi_o,
    const float* __restrict__ br_c, const float* __restrict__ bi_c,
    short* __restrict__ Wp, float* __restrict__ bias) {
  __shared__ short tile[64 * 72];
  int blk = blockIdx.x;
  int tid = threadIdx.x;

  if (blk < 520) {                        // ---- halo zero
    int t = blk * 256 + tid;              // 4160 px * 32
    int s   = t & 31;
    int pix = t >> 5;
    int b = pix / 260;
    int r = pix - b * 260;
    int yp, xp;
    if (r < 66)       { yp = 0;               xp = r; }
    else if (r < 132) { yp = 65;              xp = r - 66; }
    else { int r2 = r - 132; yp = 1 + (r2 >> 1); xp = (r2 & 1) * 65; }
    short8 z;
#pragma unroll
    for (int q = 0; q < 8; ++q) z[q] = 0;
    *(short8*)(Zp + (((b * 66 + yp) * 66 + xp) * 256 + s * 8)) = z;
    return;
  }

  if (blk < 520 + 4096) {                 // ---- pack Z (tiled transpose)
    int bid = blk - 520;
    int y      = bid & 63;
    int half   = (bid >> 6) & 1;
    int srcSel = (bid >> 7) & 1;
    int b      = bid >> 8;
    const float* src = srcSel ? hs : xs;
    int chBase  = half * 64;
    int cinBase = half * 128 + srcSel * 64;
    int x4 = tid & 15, chq = tid >> 4;
#pragma unroll
    for (int p = 0; p < 4; ++p) {
      int ch = p * 16 + chq;
      float4v f = *(const float4v*)(src + (size_t)(b * 128 + chBase + ch) * 4096 + y * 64 + x4 * 4);
#pragma unroll
      for (int e = 0; e < 4; ++e)
        tile[(x4 * 4 + e) * 72 + ch] = f2bf(f[e]);
    }
    __syncthreads();
    int x = tid >> 2, seg = tid & 3;
    short8 v0 = *(const short8*)(tile + x * 72 + seg * 16);
    short8 v1 = *(const short8*)(tile + x * 72 + seg * 16 + 8);
    size_t outp = ((size_t)(b * 66 + y + 1) * 66 + x + 1) * 256 + cinBase + seg * 16;
    *(short8*)(Zp + outp)     = v0;
    *(short8*)(Zp + outp + 8) = v1;
    return;
  }

  {                                       // ---- pack W + bias
    int g = (blk - 4616) * 256 + tid;
    if (g >= 384 * 9 * 256) return;
    int cin = g & 255;
    int tap = (g >> 8) % 9;
    int n   = g / (256 * 9);
    int part = n >> 6, ch = n & 63;
    const float *Wr, *Wi;
    if (part < 2)      { Wr = Wr_i; Wi = Wi_i; }
    else if (part < 4) { Wr = Wr_o; Wi = Wi_o; }
    else               { Wr = Wr_c; Wi = Wi_c; }
    int im = part & 1;
    int ci = cin & 127;
    int second = cin >> 7;
    const float* src = im ? (second ? Wr : Wi) : (second ? Wi : Wr);
    float f = src[(ch * 128 + ci) * 9 + tap];
    if (!im && second) f = -f;
    Wp[(n * 9 + tap) * 256 + cin] = f2bf(f);
    if (g < 384) {
      int p2 = g >> 6, c2 = g & 63;
      const float* bs = (p2 == 0) ? br_i : (p2 == 1) ? bi_i : (p2 == 2) ? br_o
                      : (p2 == 3) ? bi_o : (p2 == 4) ? br_c : bi_c;
      bias[g] = bs[c2];
    }
  }
}

// ---------------------------------------------------------------- conv + fused epilogue
// A stage: 384 rows x 4 slots (16B, 8 k each) = 1536 slots, 3 gload/thread.
//   slot = row*4 + p, p holds k-group p^(row&3).
// B stage: 4 rows x 66 cols x 4 slots = 1056 slots; interior 1024 = 2 chunks
//   of 512 (1 gload/thread); slot = row*264 + col*4 + p, p holds p^(col&3);
//   halo cols 0/65 zeroed once (both buffers).
__device__ __forceinline__ void issueA(const short* __restrict__ Wp, int tapkc,
                                       short8* dst, int tid, int wv) {
#pragma unroll
  for (int it = 0; it < 3; ++it) {
    int idx = tid + it * 512;
    int row = idx >> 2, p = idx & 3;
    int g = p ^ (row & 3);
    gload16(Wp + ((size_t)row * 2304 + tapkc + g * 8),
            (void*)(dst + (it * 512 + wv * 64)));
  }
}

__device__ __forceinline__ void issueBc(const short* __restrict__ Z, int zrow0,
                                        int kcn32, int tapc, short8* dst,
                                        int tid, int wv) {
  int idx = tapc * 512 + tid;
  int row = idx >> 8;
  int rem = idx & 255;
  int col = 1 + (rem >> 2);
  int p   = idx & 3;
  int g   = p ^ (col & 3);
  int base = tapc * 512 + wv * 64;        // wave-uniform dest base
  int rowu = base >> 8;                   // == row (wave-constant)
  gload16(Z + ((size_t)((zrow0 + row) * 66 + col) * 256 + kcn32 + g * 8),
          (void*)(dst + (base + rowu * 8 + 4)));
}

template<int DYN, int DXN>
__device__ __forceinline__ void readFrags(const short8* __restrict__ Ab,
                                          const short8* __restrict__ Bb0,
                                          short8 (&af)[6], short8 (&bf)[4],
                                          int aBase, int wpx, int l15, int l4) {
  const short8* Bb = Bb0 + (wpx + DYN) * 264;
  int bb = (l15 + DXN) * 4 + (l4 ^ ((l15 + DXN) & 3));
#pragma unroll
  for (int i = 0; i < 6; ++i) af[i] = Ab[aBase + i * 64];
#pragma unroll
  for (int j = 0; j < 4; ++j) bf[j] = Bb[bb + j * 64];
}

__device__ __forceinline__ void mfma24(const short8 (&af)[6], const short8 (&bf)[4],
                                       floatx4 (&acc)[6][4]) {
  __builtin_amdgcn_s_setprio(1);
#pragma unroll
  for (int i = 0; i < 6; ++i)
#pragma unroll
    for (int j = 0; j < 4; ++j)
      acc[i][j] = __builtin_amdgcn_mfma_f32_16x16x32_bf16(af[i], bf[j], acc[i][j], 0, 0, 0);
  __builtin_amdgcn_s_setprio(0);
}

__device__ __forceinline__ float fsig(float v) { return 1.f / (1.f + __expf(-v)); }
__device__ __forceinline__ float ftanh(float v) {
  float e = __expf(2.f * v);
  return 1.f - 2.f / (e + 1.f);
}

__global__ __launch_bounds__(512, 2) void conv_fused(
    const short* __restrict__ Z, const short* __restrict__ Wp,
    const float* __restrict__ bias, const float* __restrict__ x,
    const float* __restrict__ c_prev, float* __restrict__ out) {
  __shared__ short8 As[2][1536];   // 49,152 B (also epilogue exchange buffer)
  __shared__ short8 Bs[2][1056];   // 33,792 B

  const int tid = threadIdx.x;
  const int wv = tid >> 6, lane = tid & 63;
  const int l15 = lane & 15, l4 = lane >> 4;
  const int wc4 = wv & 3;          // ch-quarter: rows wc4*96 .. +95
  const int wpx = wv >> 2;         // px y-row 0/1
  const int pb = blockIdx.x;
  const int b  = pb >> 5;          // batch
  const int y0 = (pb & 31) * 2;    // first output row
  const int zrow0 = b * 66 + y0;   // padded rows y0..y0+3 = inputs y0-1..y0+2

  const int aBase = (wc4 * 96 + l15) * 4 + (l4 ^ (l15 & 3));

  floatx4 acc[6][4];
#pragma unroll
  for (int i = 0; i < 6; ++i)
#pragma unroll
    for (int j = 0; j < 4; ++j)
#pragma unroll
      for (int r = 0; r < 4; ++r) acc[i][j][r] = 0.f;

  short8 afA[6], bfA[4], afB[6], bfB[4];

  // -- prologue: zero permanent halo cols (both B bufs); stage A[0], B[kc0], A[1].
  if (tid < 64) {
    int buf = tid >> 5, w = tid & 31;
    int r = w >> 3, hi = (w >> 2) & 1, p = w & 3;
    short8 z;
#pragma unroll
    for (int q = 0; q < 8; ++q) z[q] = 0;
    Bs[buf][r * 264 + (hi ? 260 : 0) + p] = z;
  }
  issueA(Wp, 0, &As[0][0], tid, wv);            // A[0] = (kc0, tap0)
  issueBc(Z, zrow0, 0, 0, &Bs[0][0], tid, wv);  // B[kc0] chunk 0
  issueBc(Z, zrow0, 0, 1, &Bs[0][0], tid, wv);  // B[kc0] chunk 1
  issueA(Wp, 256, &As[1][0], tid, wv);          // A[1] = (kc0, tap1)
  __builtin_amdgcn_sched_barrier(0);
  asm volatile("s_waitcnt vmcnt(3) lgkmcnt(0)" ::: "memory");  // A0,B0 landed; keep A1
  __builtin_amdgcn_sched_barrier(0);
  __builtin_amdgcn_s_barrier();
  __builtin_amdgcn_sched_barrier(0);
  readFrags<0, 0>(&As[0][0], &Bs[0][0], afA, bfA, aBase, wpx, l15, l4);

  // STEP s = kc*9 + TAP. PS = s&1 = (TAP+PE)&1, PE = kc&1.
  // top: vmcnt(1 at TAP 1,2 else 0)+lgkm(0)+barrier; read frags(s+1);
  // issue A[s+2] -> As[PS]; issue B chunk (TAP 0,1) -> Bs[PE^1]; MFMA(s).
  // All issues/reads unconditional (kc=8 junk is in-bounds, dead-buffered).
#define STEP(TAP, PE, KCV)                                                     \
  {                                                                            \
    constexpr int PS   = ((TAP) + (PE)) & 1;                                   \
    constexpr int TAPN = ((TAP) + 1) % 9;                                      \
    constexpr int PBN  = ((TAP) == 8) ? ((PE) ^ 1) : (PE);                     \
    if constexpr ((TAP) == 1 || (TAP) == 2)                                    \
      asm volatile("s_waitcnt vmcnt(1) lgkmcnt(0)" ::: "memory");              \
    else                                                                       \
      asm volatile("s_waitcnt vmcnt(0) lgkmcnt(0)" ::: "memory");              \
    __builtin_amdgcn_sched_barrier(0);                                         \
    __builtin_amdgcn_s_barrier();                                              \
    __builtin_amdgcn_sched_barrier(0);                                         \
    if constexpr (PS == 0)                                                     \
      readFrags<TAPN / 3, TAPN % 3>(&As[1][0], &Bs[PBN][0], afB, bfB,          \
                                    aBase, wpx, l15, l4);                      \
    else                                                                       \
      readFrags<TAPN / 3, TAPN % 3>(&As[0][0], &Bs[PBN][0], afA, bfA,          \
                                    aBase, wpx, l15, l4);                      \
    { const int kc2 = ((TAP) <= 6) ? (KCV) : (KCV) + 1;                        \
      issueA(Wp, (((TAP) + 2) % 9) * 256 + kc2 * 32, &As[PS][0], tid, wv); }   \
    if constexpr ((TAP) == 0 || (TAP) == 1)                                    \
      issueBc(Z, zrow0, ((KCV) + 1) * 32, (TAP), &Bs[(PE) ^ 1][0], tid, wv);   \
    if constexpr (PS == 0) mfma24(afA, bfA, acc);                              \
    else                   mfma24(afB, bfB, acc);                              \
  }

  for (int kq = 0; kq < 4; ++kq) {
    const int kE = kq * 2, kO = kE + 1;
    STEP(0, 0, kE) STEP(1, 0, kE) STEP(2, 0, kE) STEP(3, 0, kE) STEP(4, 0, kE)
    STEP(5, 0, kE) STEP(6, 0, kE) STEP(7, 0, kE) STEP(8, 0, kE)
    STEP(0, 1, kO) STEP(1, 1, kO) STEP(2, 1, kO) STEP(3, 1, kO) STEP(4, 1, kO)
    STEP(5, 1, kO) STEP(6, 1, kO) STEP(7, 1, kO) STEP(8, 1, kO)
  }
#undef STEP

  // -- fused epilogue: drain junk DMAs, then per-px-row exchange + gate math.
  asm volatile("s_waitcnt vmcnt(0) lgkmcnt(0)" ::: "memory");
  __syncthreads();
  short* Ex = (short*)&As[0][0];   // 384 ch x 64 x bf16 = 49,152 B
#pragma unroll
  for (int l = 0; l < 2; ++l) {
    if (wpx == l) {
#pragma unroll
      for (int i = 0; i < 6; ++i)
#pragma unroll
        for (int j = 0; j < 4; ++j)
#pragma unroll
          for (int rr = 0; rr < 4; ++rr) {
            int ch = wc4 * 96 + i * 16 + l4 * 4 + rr;
            int xx = j * 16 + l15;
            Ex[ch * 64 + xx] = f2bf(acc[i][j][rr] + bias[ch]);
          }
    }
    __syncthreads();
    {
      int xg = tid & 63, cg = tid >> 6;   // 512 threads x 8 cells
#pragma unroll
      for (int k = 0; k < 8; ++k) {
        int c = cg * 8 + k;
        float yri = bf2f(Ex[(0 * 64 + c) * 64 + xg]);
        float yii = bf2f(Ex[(1 * 64 + c) * 64 + xg]);
        float yro = bf2f(Ex[(2 * 64 + c) * 64 + xg]);
        float yio = bf2f(Ex[(3 * 64 + c) * 64 + xg]);
        float yrc = bf2f(Ex[(4 * 64 + c) * 64 + xg]);
        float yic = bf2f(Ex[(5 * 64 + c) * 64 + xg]);
        float i_r = fsig(yri), i_i = fsig(yii);
        float o_r = fsig(yro), o_i = fsig(yio);
        float ct_r = ftanh(yrc), ct_i = ftanh(yic);
        int base = (b * 128 + c) * 4096 + (y0 + l) * 64 + xg;
        float xr = x[base];
        float xi = x[base + 64 * 4096];
        float cr = c_prev[base];
        float ci = c_prev[base + 64 * 4096];
        float cnr = xr * cr - xi * ci + i_r * ct_r - i_i * ct_i;
        float cni = xr * ci + xi * cr + i_r * ct_i + i_i * ct_r;
        float tr = ftanh(cnr), ti = ftanh(cni);
        out[base]                     = o_r * tr - o_i * ti;
        out[base + 64 * 4096]         = o_r * ti + o_i * tr;
        out[HSIZE + base]             = cnr;
        out[HSIZE + base + 64 * 4096] = cni;
      }
    }
    __syncthreads();
  }
}

// ---------------------------------------------------------------- launch
extern "C" void kernel_launch(void* const* d_in, const int* in_sizes, int n_in,
                              void* d_out, int out_size, void* d_ws, size_t ws_size,
                              hipStream_t stream) {
  // inputs: 0 x, 1 h_prev, 2 c_prev,
  //         3 Wr_i, 4 Wi_i, 5 br_i, 6 bi_i,  7..10 f-gate (unused),
  //        11 Wr_o,12 Wi_o,13 br_o,14 bi_o, 15 Wr_c,16 Wi_c,17 br_c,18 bi_c
  char* ws = (char*)d_ws;
  short* Zp   = (short*)ws;                          // 35,684,352 B
  short* Wp   = (short*)(ws + 35684352);             //  1,769,472 B
  float* bias = (float*)(ws + 37453824);             //      1,536 B

  prep_kernel<<<8072, 256, 0, stream>>>(
      (const float*)d_in[0], (const float*)d_in[1], Zp,
      (const float*)d_in[3], (const float*)d_in[4],
      (const float*)d_in[11], (const float*)d_in[12],
      (const float*)d_in[15], (const float*)d_in[16],
      (const float*)d_in[5], (const float*)d_in[6],
      (const float*)d_in[13], (const float*)d_in[14],
      (const float*)d_in[17], (const float*)d_in[18],
      Wp, bias);
  conv_fused<<<512, 512, 0, stream>>>(
      Zp, Wp, bias, (const float*)d_in[0], (const float*)d_in[2],
      (float*)d_out);
}